// Round 15
// baseline (418.937 us; speedup 1.0000x reference)
//
#include <hip/hip_runtime.h>
#include <math.h>

typedef unsigned short u16;
typedef __attribute__((ext_vector_type(8))) short bf16x8;
typedef __attribute__((ext_vector_type(4))) float f32x4;

#define MFMA16(a,b,c) __builtin_amdgcn_mfma_f32_16x16x32_bf16(a,b,c,0,0,0)

__device__ __forceinline__ u16 f2bf(float f){
  union { float f; unsigned int u; } x; x.f = f;
  unsigned int r = x.u + 0x7fffu + ((x.u >> 16) & 1u);
  return (u16)(r >> 16);
}

__device__ __forceinline__ void gload16(const void* g, void* lds){
  __builtin_amdgcn_global_load_lds(
    (const __attribute__((address_space(1))) unsigned int*)g,
    (__attribute__((address_space(3))) unsigned int*)lds, 16, 0, 0);
}

// ---------------- weights fp32 -> bf16 ---------------------------------------
__global__ __launch_bounds__(256) void cvt_weights(
    const float* __restrict__ wqkv, const float* __restrict__ wo,
    const float* __restrict__ w1, const float* __restrict__ w2,
    u16* __restrict__ o0, u16* __restrict__ o1,
    u16* __restrict__ o2, u16* __restrict__ o3)
{
  int idx = blockIdx.x * 256 + threadIdx.x;   // quad index, 3145728 total
  const float* src; u16* dst;
  if (idx < 786432)                    { src = wqkv; dst = o0; }
  else if ((idx -= 786432) < 262144)   { src = wo;   dst = o1; }
  else if ((idx -= 262144) < 1048576)  { src = w1;   dst = o2; }
  else { idx -= 1048576;                 src = w2;   dst = o3; }
  float4 v = ((const float4*)src)[idx];
  short4 o;
  o.x = (short)f2bf(v.x); o.y = (short)f2bf(v.y);
  o.z = (short)f2bf(v.z); o.w = (short)f2bf(v.w);
  ((short4*)dst)[idx] = o;
}

// ---------------- layernorm over D=1024, out bf16 ----------------------------
template<int MODE>
__global__ __launch_bounds__(256) void ln_kernel(
    const float* __restrict__ s0, const float* __restrict__ s1,
    const float* __restrict__ g, const float* __restrict__ be,
    u16* __restrict__ out)
{
  int row = blockIdx.x, t = threadIdx.x;
  const float* src;
  if (MODE == 1) {
    int b = row >> 11, p = row & 2047;
    src = (p < 1024) ? s0 + ((long)(b*1024 + p))*1024
                     : s1 + ((long)(b*1024 + p - 1024))*1024;
  } else {
    src = s0 + (long)row * 1024;
  }
  float4 v = ((const float4*)src)[t];
  float s  = v.x + v.y + v.z + v.w;
  float ss = v.x*v.x + v.y*v.y + v.z*v.z + v.w*v.w;
  #pragma unroll
  for (int m = 1; m < 64; m <<= 1) { s += __shfl_xor(s, m); ss += __shfl_xor(ss, m); }
  __shared__ float red[8];
  int l = t & 63, w = t >> 6;
  if (l == 0) { red[w*2] = s; red[w*2+1] = ss; }
  __syncthreads();
  s  = red[0] + red[2] + red[4] + red[6];
  ss = red[1] + red[3] + red[5] + red[7];
  float mean = s * (1.0f/1024.0f);
  float var  = ss * (1.0f/1024.0f) - mean*mean;
  float rstd = rsqrtf(var + 1e-5f);
  float4 gv = ((const float4*)g)[t];
  float4 bv = ((const float4*)be)[t];
  short4 o;
  o.x = (short)f2bf((v.x-mean)*rstd*gv.x + bv.x);
  o.y = (short)f2bf((v.y-mean)*rstd*gv.y + bv.y);
  o.z = (short)f2bf((v.z-mean)*rstd*gv.z + bv.z);
  o.w = (short)f2bf((v.w-mean)*rstd*gv.w + bv.w);
  *(short4*)(out + (long)row*1024 + t*4) = o;
}

// ---------------- bf16 GEMM 128-class (ffn2) ---------------------------------
template<int EPI, int BM>
__global__ __launch_bounds__(256,2) void gemm_bt(
    const u16* __restrict__ A, const u16* __restrict__ Bt,
    int M, int N, int K,
    const float* __restrict__ bias,
    const float* __restrict__ gamma,
    const float* __restrict__ resid,
    float* __restrict__ outf,
    u16* __restrict__ outb0, u16* __restrict__ outb1)
{
  constexpr int MI = BM / 32;
  __shared__ __align__(16) u16 at[2][BM*64];
  __shared__ __align__(16) u16 bt[2][128*64];
  int nwg = gridDim.x;
  int bidx = (blockIdx.x & 7) * (nwg >> 3) + (blockIdx.x >> 3);
  int nb = N >> 7;
  int tm = bidx / nb, tn = bidx % nb;
  int m0 = tm * BM, n0 = tn << 7;
  int t = threadIdx.x, l = t & 63, w = t >> 6;
  int wr = (w >> 1) * (BM/2), wc = (w & 1) * 64;
  int fr = l & 15, fq = l >> 4;
  f32x4 acc[MI][4] = {};
  int rr = t >> 3;
  int cb = (t & 7) << 4;
  const char* Ab = (const char*)A;
  const char* Bp = (const char*)Bt;
  long ld = (long)K * 2;

#define G_STAGE(s, kt) do {                                                        \
    _Pragma("unroll")                                                              \
    for (int c = 0; c < MI; c++) {                                                 \
      int row = c*32 + rr;                                                         \
      gload16(Ab + (long)(m0 + row)*ld + (long)(kt)*2 + (cb ^ ((row & 7) << 4)),   \
              (char*)at[s] + c*4096 + w*1024);                                     \
    }                                                                              \
    _Pragma("unroll")                                                              \
    for (int c = 0; c < 4; c++) {                                                  \
      int row = c*32 + rr;                                                         \
      gload16(Bp + (long)(n0 + row)*ld + (long)(kt)*2 + (cb ^ ((row & 7) << 4)),   \
              (char*)bt[s] + c*4096 + w*1024);                                     \
    }                                                                              \
  } while (0)

  G_STAGE(0, 0);
  __syncthreads();
  int cur = 0;
  for (int kt = 0; kt < K; kt += 64) {
    if (kt + 64 < K) G_STAGE(cur ^ 1, kt + 64);
    #pragma unroll
    for (int ka = 0; ka < 2; ka++) {
      bf16x8 af[MI], bfv[4];
      #pragma unroll
      for (int i = 0; i < MI; i++) {
        int ra = wr + i*16 + fr;
        af[i] = *(const bf16x8*)((const char*)at[cur] + ra*128 + ((ka*64 + fq*16) ^ ((ra & 7) << 4)));
      }
      #pragma unroll
      for (int j = 0; j < 4; j++) {
        int rb = wc + j*16 + fr;
        bfv[j] = *(const bf16x8*)((const char*)bt[cur] + rb*128 + ((ka*64 + fq*16) ^ ((rb & 7) << 4)));
      }
      #pragma unroll
      for (int i = 0; i < MI; i++)
        #pragma unroll
        for (int j = 0; j < 4; j++)
          acc[i][j] = MFMA16(af[i], bfv[j], acc[i][j]);
    }
    __syncthreads();
    cur ^= 1;
  }
#undef G_STAGE
  #pragma unroll
  for (int i = 0; i < MI; i++) {
    #pragma unroll
    for (int j = 0; j < 4; j++) {
      #pragma unroll
      for (int r = 0; r < 4; r++) {
        int row = m0 + wr + i*16 + fq*4 + r;
        int col = n0 + wc + j*16 + fr;
        float v = acc[i][j][r];
        if constexpr (EPI == 3) {
          float u = v + bias[col];
          float ge = 0.5f * u * (1.0f + erff(u * 0.70710678118654752f));
          outb0[(long)row*4096 + col] = f2bf(ge);
        } else {  // EPI 4: ffn2 resid
          float gs = gamma[col]; gs = fminf(fmaxf(gs, -10.f), 10.f);
          long idx = (long)row*1024 + col;
          outf[idx] = resid[idx] + (v + bias[col]) * gs;
        }
      }
    }
  }
}

// ======= 256^2-tile 8-phase core (shared by gemm256 and gemm256_qkv) =========
#define STAGE_AQ(slot, kt, q) do {                                               \
    int grow = (sr < 32) ? ((q)*32 + sr) : (128 + (q)*32 + sr - 32);             \
    int abase = (w < 4) ? ((q)*32 + w*8) : (128 + (q)*32 + (w - 4)*8);           \
    gload16(Ab + (long)(m0 + grow)*ld + (long)(kt)*2 + (scb ^ s7),               \
            (char*)As[slot] + abase*128);                                        \
  } while (0)
#define STAGE_BH(slot, kt, h) do {                                               \
    int r0 = (h)*128 + sr;                                                       \
    gload16(Bp + (long)(n0 + r0)*ld + (long)(kt)*2 + (scb ^ s7),                 \
            (char*)Bs[slot] + ((h)*128 + w*8)*128);                              \
    gload16(Bp + (long)(n0 + r0 + 64)*ld + (long)(kt)*2 + (scb ^ s7),            \
            (char*)Bs[slot] + ((h)*128 + 64 + w*8)*128);                         \
  } while (0)
#define MFMA_PHASE(mibase)                                                       \
    __builtin_amdgcn_s_setprio(1);                                               \
    _Pragma("unroll")                                                            \
    for (int nj = 0; nj < 4; nj++) {                                             \
      acc[(mibase)][nj]   = MFMA16(a00, bfr[nj][0], acc[(mibase)][nj]);          \
      acc[(mibase)][nj]   = MFMA16(a01, bfr[nj][1], acc[(mibase)][nj]);          \
      acc[(mibase)+1][nj] = MFMA16(a10, bfr[nj][0], acc[(mibase)+1][nj]);        \
      acc[(mibase)+1][nj] = MFMA16(a11, bfr[nj][1], acc[(mibase)+1][nj]);        \
    }                                                                            \
    __builtin_amdgcn_s_setprio(0);
#define READ_A(p)                                                                \
    int r0_ = wm*128 + (2*(p))*16 + fr;                                          \
    int r1_ = r0_ + 16;                                                          \
    bf16x8 a00 = *(const bf16x8*)(Ab_s + r0_*128 + ((fq*16) ^ ((r0_ & 7) << 4)));        \
    bf16x8 a01 = *(const bf16x8*)(Ab_s + r0_*128 + ((64 + fq*16) ^ ((r0_ & 7) << 4)));   \
    bf16x8 a10 = *(const bf16x8*)(Ab_s + r1_*128 + ((fq*16) ^ ((r1_ & 7) << 4)));        \
    bf16x8 a11 = *(const bf16x8*)(Ab_s + r1_*128 + ((64 + fq*16) ^ ((r1_ & 7) << 4)));

#define GEMM256_BODY                                                             \
  f32x4 acc[8][4] = {};                                                          \
  STAGE_BH(0, 0, 0); STAGE_BH(0, 0, 1);                                          \
  STAGE_AQ(0, 0, 0); STAGE_AQ(0, 0, 1); STAGE_AQ(0, 0, 2); STAGE_AQ(0, 0, 3);    \
  STAGE_BH(1, 64, 0); STAGE_BH(1, 64, 1);                                        \
  asm volatile("s_waitcnt vmcnt(4)" ::: "memory");                               \
  __builtin_amdgcn_s_barrier();                                                  \
  asm volatile("" ::: "memory");                                                 \
  for (int tt = 0; tt < NT; tt++) {                                              \
    int s = tt & 1;                                                              \
    const char* Ab_s = (const char*)As[s];                                       \
    const char* Bb_s = (const char*)Bs[s];                                       \
    int kt1 = (tt + 1) << 6, kt2 = (tt + 2) << 6;                                \
    bf16x8 bfr[4][2];                                                            \
    {                                                                            \
      _Pragma("unroll")                                                          \
      for (int nj = 0; nj < 4; nj++) {                                           \
        int rb = wn*64 + nj*16 + fr;                                             \
        bfr[nj][0] = *(const bf16x8*)(Bb_s + rb*128 + ((fq*16) ^ ((rb & 7) << 4)));      \
        bfr[nj][1] = *(const bf16x8*)(Bb_s + rb*128 + ((64 + fq*16) ^ ((rb & 7) << 4))); \
      }                                                                          \
      READ_A(0)                                                                  \
      if (tt + 1 < NT) { STAGE_AQ(s ^ 1, kt1, 0); STAGE_AQ(s ^ 1, kt1, 1); }     \
      asm volatile("s_waitcnt lgkmcnt(8)" ::: "memory");                         \
      __builtin_amdgcn_s_barrier();                                              \
      asm volatile("s_waitcnt lgkmcnt(0)" ::: "memory");                         \
      MFMA_PHASE(0)                                                              \
      __builtin_amdgcn_s_barrier();                                              \
    }                                                                            \
    {                                                                            \
      READ_A(1)                                                                  \
      if (tt + 1 < NT) { STAGE_AQ(s ^ 1, kt1, 2); STAGE_AQ(s ^ 1, kt1, 3); }     \
      __builtin_amdgcn_s_barrier();                                              \
      asm volatile("s_waitcnt lgkmcnt(0)" ::: "memory");                         \
      MFMA_PHASE(2)                                                              \
      __builtin_amdgcn_s_barrier();                                              \
    }                                                                            \
    {                                                                            \
      READ_A(2)                                                                  \
      if (tt + 2 < NT) STAGE_BH(s, kt2, 0);                                      \
      __builtin_amdgcn_s_barrier();                                              \
      asm volatile("s_waitcnt lgkmcnt(0)" ::: "memory");                         \
      MFMA_PHASE(4)                                                              \
      __builtin_amdgcn_s_barrier();                                              \
    }                                                                            \
    {                                                                            \
      READ_A(3)                                                                  \
      if (tt + 2 < NT) STAGE_BH(s, kt2, 1);                                      \
      __builtin_amdgcn_s_barrier();                                              \
      asm volatile("s_waitcnt lgkmcnt(0)" ::: "memory");                         \
      MFMA_PHASE(6)                                                              \
      if (tt + 1 < NT) {                                                         \
        if (tt + 2 < NT) { asm volatile("s_waitcnt vmcnt(4)" ::: "memory"); }    \
        else             { asm volatile("s_waitcnt vmcnt(0)" ::: "memory"); }    \
      }                                                                          \
      __builtin_amdgcn_s_barrier();                                              \
      asm volatile("" ::: "memory");                                             \
    }                                                                            \
  }

// ---------------- ffn1 gemm256 (EPI=3) ---------------------------------------
__global__ __launch_bounds__(512, 2) void gemm256_ffn1(
    const u16* __restrict__ A, const u16* __restrict__ Bt,
    int M, int N, int K,
    const float* __restrict__ bias,
    u16* __restrict__ outb0)
{
  __shared__ __align__(16) u16 As[2][256*64];
  __shared__ __align__(16) u16 Bs[2][256*64];
  int nwg = gridDim.x;
  int bidx = (blockIdx.x & 7) * (nwg >> 3) + (blockIdx.x >> 3);
  int nb = N >> 8;
  int tm = bidx / nb, tn = bidx % nb;
  int m0 = tm << 8, n0 = tn << 8;
  int t = threadIdx.x, l = t & 63, w = t >> 6;
  int wm = w >> 2, wn = w & 3;
  int fr = l & 15, fq = l >> 4;
  int sr = t >> 3;
  int scb = (t & 7) << 4;
  int s7 = (sr & 7) << 4;
  const char* Ab = (const char*)A;
  const char* Bp = (const char*)Bt;
  long ld = (long)K * 2;
  int NT = K >> 6;
  GEMM256_BODY
  #pragma unroll
  for (int mi = 0; mi < 8; mi++)
    #pragma unroll
    for (int nj = 0; nj < 4; nj++)
      #pragma unroll
      for (int r = 0; r < 4; r++) {
        int row = m0 + wm*128 + mi*16 + fq*4 + r;
        int col = n0 + wn*64 + nj*16 + fr;
        float u = acc[mi][nj][r] + bias[col];
        float ge = 0.5f * u * (1.0f + erff(u * 0.70710678118654752f));
        outb0[(long)row*4096 + col] = f2bf(ge);
      }
}

// ---------------- grouped QKV gemm256: 256 kv-role + 64 q-role blocks --------
__global__ __launch_bounds__(512, 2) void gemm256_qkv(
    const u16* __restrict__ qin, const u16* __restrict__ kvin,
    const u16* __restrict__ wqkv_b,      // bf16 [3072][1024]
    const float* __restrict__ bias,      // 3072
    u16* __restrict__ qo, u16* __restrict__ ko, u16* __restrict__ vto)
{
  __shared__ __align__(16) u16 As[2][256*64];
  __shared__ __align__(16) u16 Bs[2][256*64];
  int nwg = gridDim.x;                 // 320
  int bidx = (blockIdx.x & 7) * (nwg >> 3) + (blockIdx.x >> 3);
  int iskv = (bidx < 256);
  int tm, tn;
  const char* Ab; const char* Bp;
  if (iskv) { tm = bidx >> 3; tn = bidx & 7;
              Ab = (const char*)kvin; Bp = (const char*)(wqkv_b + 1024L*1024); }
  else      { int i = bidx - 256; tm = i >> 2; tn = i & 3;
              Ab = (const char*)qin;  Bp = (const char*)wqkv_b; }
  int m0 = tm << 8, n0 = tn << 8;
  int t = threadIdx.x, l = t & 63, w = t >> 6;
  int wm = w >> 2, wn = w & 3;
  int fr = l & 15, fq = l >> 4;
  int sr = t >> 3;
  int scb = (t & 7) << 4;
  int s7 = (sr & 7) << 4;
  long ld = 2048;                      // K=1024
  int NT = 16;
  GEMM256_BODY
  #pragma unroll
  for (int mi = 0; mi < 8; mi++)
    #pragma unroll
    for (int nj = 0; nj < 4; nj++)
      #pragma unroll
      for (int r = 0; r < 4; r++) {
        int row = m0 + wm*128 + mi*16 + fq*4 + r;
        int col = n0 + wn*64 + nj*16 + fr;
        float v = acc[mi][nj][r];
        if (iskv) {
          float u = v + bias[1024 + col];
          int b = row >> 11, p = row & 2047;
          if (col < 1024) {
            int h = col >> 6, hd = col & 63;
            ko[(((long)((b*16 + h)*2048 + p)) << 6) + hd] = f2bf(u);
          } else {
            int c2 = col - 1024, h = c2 >> 6, hd = c2 & 63;
            vto[(((long)((b*16 + h)*64 + hd)) << 11) + p] = f2bf(u);  // V^T
          }
        } else {
          float qv = (v + bias[col]) * 0.18033688011112042f;  // (1/8)*log2(e)
          int b = row >> 10, lq = row & 1023, h = col >> 6, hd = col & 63;
          qo[(((long)(b*16 + h)) << 16) + (lq << 6) + hd] = f2bf(qv);
        }
      }
}

// ---------------- flash attention fwd (r13 version, 73us) --------------------
__global__ __launch_bounds__(256, 3) void flash_fwd(
    const u16* __restrict__ q, const u16* __restrict__ k,
    const u16* __restrict__ vt, u16* __restrict__ ctx,
    float* __restrict__ ilout)
{
  __shared__ __align__(16) u16 ks[2][64*64];
  __shared__ __align__(16) u16 vs[2][64*64];
  __shared__ __align__(16) char ps[4*4096];
  int nwg = gridDim.x;
  int bid = (blockIdx.x & 7) * (nwg >> 3) + (blockIdx.x >> 3);
  int qt = bid & 7, h = (bid >> 3) & 15, b = bid >> 7;
  int q0 = qt << 7;
  int t = threadIdx.x, l = t & 63, w = t >> 6;
  int fr = l & 15, fq = l >> 4;
  const char* qb = (const char*)(q  + (((long)(b*16 + h)) << 16));
  const char* kb = (const char*)(k  + (((long)(b*16 + h)) << 17));
  const char* vb = (const char*)(vt + (((long)(b*16 + h)) << 17));
  char* psw = ps + w*4096;
  int rr = t >> 3;
  int sc = (t & 7) << 4;

  #pragma unroll
  for (int c = 0; c < 2; c++) {
    int row = c*32 + rr;
    gload16(kb + (long)row*128 + (sc ^ ((row & 7) << 4)), (char*)ks[0] + c*4096 + w*1024);
    gload16(vb + (long)row*4096 + (sc ^ ((row & 7) << 4)), (char*)vs[0] + c*4096 + w*1024);
  }
  {
    int qr = l >> 3;
    #pragma unroll
    for (int c = 0; c < 4; c++) {
      int row = c*8 + qr;
      gload16(qb + (long)(q0 + w*32 + row)*128 + (sc ^ ((row & 7) << 4)), psw + c*1024);
    }
  }
  asm volatile("s_waitcnt vmcnt(0)" ::: "memory");
  bf16x8 qf[2][2];
  #pragma unroll
  for (int rf = 0; rf < 2; rf++) {
    int row = rf*16 + fr;
    qf[rf][0] = *(const bf16x8*)(psw + row*128 + ((fq*16) ^ ((row & 7) << 4)));
    qf[rf][1] = *(const bf16x8*)(psw + row*128 + ((64 + fq*16) ^ ((row & 7) << 4)));
  }
  asm volatile("s_waitcnt lgkmcnt(0)" ::: "memory");
  __builtin_amdgcn_s_barrier();
  asm volatile("" ::: "memory");

  f32x4 cacc[2][4] = {};
  f32x4 lrun[2] = {{0.f,0.f,0.f,0.f},{0.f,0.f,0.f,0.f}};
  int cur = 0;
  for (int kt = 0; kt < 2048; kt += 64) {
    int notlast = (kt + 64 < 2048);
    if (notlast) {
      #pragma unroll
      for (int c = 0; c < 2; c++) {
        int row = c*32 + rr;
        gload16(vb + (long)row*4096 + (long)(kt + 64)*2 + (sc ^ ((row & 7) << 4)),
                (char*)vs[cur ^ 1] + c*4096 + w*1024);
        gload16(kb + (long)(kt + 64 + row)*128 + (sc ^ ((row & 7) << 4)),
                (char*)ks[cur ^ 1] + c*4096 + w*1024);
      }
    }
    __builtin_amdgcn_sched_barrier(0);
    const char* ksb = (const char*)ks[cur];
    f32x4 sf[2][4];
    __builtin_amdgcn_s_setprio(1);
    #pragma unroll
    for (int cf = 0; cf < 4; cf++) {
      int row = cf*16 + fr;
      bf16x8 kf0 = *(const bf16x8*)(ksb + row*128 + ((fq*16) ^ ((row & 7) << 4)));
      bf16x8 kf1 = *(const bf16x8*)(ksb + row*128 + ((64 + fq*16) ^ ((row & 7) << 4)));
      #pragma unroll
      for (int rf = 0; rf < 2; rf++) {
        f32x4 a = {};
        a = MFMA16(qf[rf][0], kf0, a);
        sf[rf][cf] = MFMA16(qf[rf][1], kf1, a);
      }
    }
    __builtin_amdgcn_s_setprio(0);
    #pragma unroll
    for (int rf = 0; rf < 2; rf++)
      #pragma unroll
      for (int cf = 0; cf < 4; cf++)
        #pragma unroll
        for (int r = 0; r < 4; r++) {
          float pv = exp2f(sf[rf][cf][r]);
          lrun[rf][r] += pv;
          union { float f; unsigned int u; } pu; pu.f = pv;
          int prow = rf*16 + fq*4 + r;
          *(u16*)(psw + prow*128 + (((cf*16 + fr) << 1) ^ ((prow & 7) << 4))) = (u16)(pu.u >> 16);
        }
    bf16x8 pa[2][2];
    #pragma unroll
    for (int rf = 0; rf < 2; rf++) {
      int row = rf*16 + fr;
      pa[rf][0] = *(const bf16x8*)(psw + row*128 + ((fq*16) ^ ((row & 7) << 4)));
      pa[rf][1] = *(const bf16x8*)(psw + row*128 + ((64 + fq*16) ^ ((row & 7) << 4)));
    }
    __builtin_amdgcn_s_setprio(1);
    #pragma unroll
    for (int cfd = 0; cfd < 4; cfd++) {
      int hd = cfd*16 + fr;
      bf16x8 vf0 = *(const bf16x8*)((const char*)vs[cur] + hd*128 + ((fq*16) ^ ((hd & 7) << 4)));
      bf16x8 vf1 = *(const bf16x8*)((const char*)vs[cur] + hd*128 + ((64 + fq*16) ^ ((hd & 7) << 4)));
      #pragma unroll
      for (int rf = 0; rf < 2; rf++) {
        cacc[rf][cfd] = MFMA16(pa[rf][0], vf0, cacc[rf][cfd]);
        cacc[rf][cfd] = MFMA16(pa[rf][1], vf1, cacc[rf][cfd]);
      }
    }
    __builtin_amdgcn_s_setprio(0);
    if (notlast) {
      asm volatile("s_waitcnt vmcnt(0)" ::: "memory");
      __builtin_amdgcn_s_barrier();
      asm volatile("" ::: "memory");
    }
    cur ^= 1;
  }
  #pragma unroll
  for (int rf = 0; rf < 2; rf++) {
    float il4[4];
    #pragma unroll
    for (int r = 0; r < 4; r++) {
      float s = lrun[rf][r];
      #pragma unroll
      for (int msk = 1; msk < 16; msk <<= 1) s += __shfl_xor(s, msk, 16);
      il4[r] = 1.0f / s;
    }
    #pragma unroll
    for (int cf = 0; cf < 4; cf++)
      #pragma unroll
      for (int r = 0; r < 4; r++) {
        int row = q0 + w*32 + rf*16 + fq*4 + r;
        int col = h*64 + cf*16 + fr;
        ctx[(long)(b*1024 + row)*1024 + col] = f2bf(cacc[rf][cf][r] * il4[r]);
      }
    if (fr == 0) {
      #pragma unroll
      for (int r = 0; r < 4; r++) {
        int row = q0 + w*32 + rf*16 + fq*4 + r;
        long idx = (((long)(b*16 + h)) << 10) + row;
        ilout[idx] = il4[r];
      }
    }
  }
}

// ---------------- fused post-attention: attn_mean (even) + oproj (odd) -------
// Both depend only on flash outputs and are independent; interleaving roles
// per-CU lets the trans/VALU-heavy attn_mean overlap the MFMA/mem-heavy oproj
// (m114: separate pipes co-schedule). LDS = union(65KB attn, 48KB oproj).
__global__ __launch_bounds__(256, 2) void post_attn(
    const u16* __restrict__ q, const u16* __restrict__ k,
    const float* __restrict__ il, float* __restrict__ mean_out,
    const u16* __restrict__ ctx, const u16* __restrict__ wo_b,
    const float* __restrict__ bo, const float* __restrict__ cg,
    const float* __restrict__ tight, float* __restrict__ x_f)
{
  __shared__ __align__(16) char smem[66560];
  int nwg = gridDim.x;   // 1024
  int bidx = (blockIdx.x & 7) * (nwg >> 3) + (blockIdx.x >> 3);
  int t = threadIdx.x, l = t & 63, w = t >> 6;
  int fr = l & 15, fq = l >> 4;

  if ((bidx & 1) == 0) {
    // ================= attn_mean role (bid 0..511) =================
    int bid = bidx >> 1;
    u16 (*qs)[128*64] = (u16 (*)[128*64])smem;
    u16 (*ks)[128*64] = (u16 (*)[128*64])(smem + 32768);
    float (*ml)[128]  = (float (*)[128])(smem + 65536);
    int kt = bid & 15, qt = (bid >> 4) & 7, b = bid >> 7;
    int q0 = qt << 7, k0 = kt << 7;
    int wr = (w >> 1) << 6, wc = (w & 1) << 6;
    int rr = t >> 3, cbb = (t & 7) << 4;
    const long bh = (long)b * 16;

#define AM_STAGE(hh, s) do {                                                        \
    const char* qb_ = (const char*)(q + ((bh + (hh)) << 16)) + (long)q0*128;        \
    const char* kb_ = (const char*)(k + ((bh + (hh)) << 17)) + (long)k0*128;        \
    _Pragma("unroll")                                                               \
    for (int c = 0; c < 4; c++) {                                                   \
      int row = c*32 + rr;                                                          \
      int sw = cbb ^ ((row & 7) << 4);                                              \
      gload16(qb_ + (long)row*128 + sw, (char*)qs[s] + c*4096 + w*1024);            \
      gload16(kb_ + (long)row*128 + sw, (char*)ks[s] + c*4096 + w*1024);            \
    }                                                                               \
    if (w == 0 && l < 32) {                                                         \
      gload16((const char*)(il + ((bh + (hh)) << 10) + q0) + l*16, (char*)ml[s]);   \
    }                                                                               \
  } while (0)

    AM_STAGE(0, 0);
    asm volatile("s_waitcnt vmcnt(0)" ::: "memory");
    __builtin_amdgcn_s_barrier();
    asm volatile("" ::: "memory");

    f32x4 macc[4][4] = {};
    for (int h = 0; h < 16; h++) {
      int cur = h & 1;
      if (h < 15) AM_STAGE(h + 1, cur ^ 1);
      const char* qsb = (const char*)qs[cur];
      const char* ksb = (const char*)ks[cur];
      const float* mlb = ml[cur];
      f32x4 ir4[4];
      #pragma unroll
      for (int i = 0; i < 4; i++)
        ir4[i] = *(const f32x4*)(mlb + wr + i*16 + fq*4);
      bf16x8 af[4][2], bf[4][2];
      #pragma unroll
      for (int i = 0; i < 4; i++) {
        int ra = wr + i*16 + fr;
        int rb = wc + i*16 + fr;
        af[i][0] = *(const bf16x8*)(qsb + ra*128 + ((fq*16) ^ ((ra & 7) << 4)));
        af[i][1] = *(const bf16x8*)(qsb + ra*128 + ((64 + fq*16) ^ ((ra & 7) << 4)));
        bf[i][0] = *(const bf16x8*)(ksb + rb*128 + ((fq*16) ^ ((rb & 7) << 4)));
        bf[i][1] = *(const bf16x8*)(ksb + rb*128 + ((64 + fq*16) ^ ((rb & 7) << 4)));
      }
      #pragma unroll
      for (int j = 0; j < 4; j++) {
        f32x4 sf[4];
        __builtin_amdgcn_s_setprio(1);
        #pragma unroll
        for (int i = 0; i < 4; i++) {
          f32x4 a = MFMA16(af[i][0], bf[j][0], {});
          sf[i] = MFMA16(af[i][1], bf[j][1], a);
        }
        __builtin_amdgcn_s_setprio(0);
        #pragma unroll
        for (int i = 0; i < 4; i++)
          #pragma unroll
          for (int r = 0; r < 4; r++)
            macc[i][j][r] += exp2f(sf[i][r]) * ir4[i][r];
      }
      asm volatile("s_waitcnt vmcnt(0)" ::: "memory");
      __builtin_amdgcn_s_barrier();
      asm volatile("" ::: "memory");
    }
#undef AM_STAGE
    #pragma unroll
    for (int i = 0; i < 4; i++)
      #pragma unroll
      for (int j = 0; j < 4; j++)
        #pragma unroll
        for (int r = 0; r < 4; r++) {
          int row = q0 + wr + i*16 + fq*4 + r;
          int col = k0 + wc + j*16 + fr;
          mean_out[((long)(b*1024 + row) << 11) + col] = macc[i][j][r] * 0.0625f;
        }
  } else {
    // ================= oproj role (bid 0..511), BM=64 =================
    int bid = bidx >> 1;
    u16 (*at)[64*64]  = (u16 (*)[64*64])smem;
    u16 (*bt)[128*64] = (u16 (*)[128*64])(smem + 16384);
    int tm = bid >> 3, tn = bid & 7;     // M=4096/64=64, N=1024/128=8
    int m0 = tm << 6, n0 = tn << 7;
    int wr = (w >> 1) * 32, wc = (w & 1) * 64;
    f32x4 acc[2][4] = {};
    int rr = t >> 3;
    int cb = (t & 7) << 4;
    const char* Ab = (const char*)ctx;
    const char* Bp = (const char*)wo_b;
    long ld = 2048;                      // K=1024

#define O_STAGE(s, kt) do {                                                        \
    _Pragma("unroll")                                                              \
    for (int c = 0; c < 2; c++) {                                                  \
      int row = c*32 + rr;                                                         \
      gload16(Ab + (long)(m0 + row)*ld + (long)(kt)*2 + (cb ^ ((row & 7) << 4)),   \
              (char*)at[s] + c*4096 + w*1024);                                     \
    }                                                                              \
    _Pragma("unroll")                                                              \
    for (int c = 0; c < 4; c++) {                                                  \
      int row = c*32 + rr;                                                         \
      gload16(Bp + (long)(n0 + row)*ld + (long)(kt)*2 + (cb ^ ((row & 7) << 4)),   \
              (char*)bt[s] + c*4096 + w*1024);                                     \
    }                                                                              \
  } while (0)

    O_STAGE(0, 0);
    __syncthreads();
    int cur = 0;
    for (int kt = 0; kt < 1024; kt += 64) {
      if (kt + 64 < 1024) O_STAGE(cur ^ 1, kt + 64);
      #pragma unroll
      for (int ka = 0; ka < 2; ka++) {
        bf16x8 af[2], bfv[4];
        #pragma unroll
        for (int i = 0; i < 2; i++) {
          int ra = wr + i*16 + fr;
          af[i] = *(const bf16x8*)((const char*)at[cur] + ra*128 + ((ka*64 + fq*16) ^ ((ra & 7) << 4)));
        }
        #pragma unroll
        for (int j = 0; j < 4; j++) {
          int rb = wc + j*16 + fr;
          bfv[j] = *(const bf16x8*)((const char*)bt[cur] + rb*128 + ((ka*64 + fq*16) ^ ((rb & 7) << 4)));
        }
        #pragma unroll
        for (int i = 0; i < 2; i++)
          #pragma unroll
          for (int j = 0; j < 4; j++)
            acc[i][j] = MFMA16(af[i], bfv[j], acc[i][j]);
      }
      __syncthreads();
      cur ^= 1;
    }
#undef O_STAGE
    #pragma unroll
    for (int i = 0; i < 2; i++)
      #pragma unroll
      for (int j = 0; j < 4; j++)
        #pragma unroll
        for (int r = 0; r < 4; r++) {
          int row = m0 + wr + i*16 + fq*4 + r;
          int col = n0 + wc + j*16 + fr;
          float gs = cg[col]; gs = fminf(fmaxf(gs, -10.f), 10.f);
          long idx = (long)row*1024 + col;
          x_f[idx] = tight[idx] + (acc[i][j][r] + bo[col]) * gs;
        }
  }
}

extern "C" void kernel_launch(void* const* d_in, const int* in_sizes, int n_in,
                              void* d_out, int out_size, void* d_ws, size_t ws_size,
                              hipStream_t stream)
{
  (void)in_sizes; (void)n_in; (void)out_size; (void)ws_size;
  const float* tight = (const float*)d_in[0];
  const float* ctxt  = (const float*)d_in[1];
  const float* nbh   = (const float*)d_in[2];
  const float* lnqg  = (const float*)d_in[3];
  const float* lnqb  = (const float*)d_in[4];
  const float* lnkg  = (const float*)d_in[5];
  const float* lnkb  = (const float*)d_in[6];
  const float* wqkv  = (const float*)d_in[7];
  const float* bqkv  = (const float*)d_in[8];
  const float* wo    = (const float*)d_in[9];
  const float* bo    = (const float*)d_in[10];
  const float* cg    = (const float*)d_in[11];
  const float* lnfg  = (const float*)d_in[12];
  const float* lnfb  = (const float*)d_in[13];
  const float* w1    = (const float*)d_in[14];
  const float* b1    = (const float*)d_in[15];
  const float* w2    = (const float*)d_in[16];
  const float* b2    = (const float*)d_in[17];
  const float* fg    = (const float*)d_in[18];

  char* p = (char*)d_ws;
  u16* wqkv_bf = (u16*)p; p += 3072L*1024*2;
  u16* wo_bf   = (u16*)p; p += 1024L*1024*2;
  u16* w1_bf   = (u16*)p; p += 4096L*1024*2;
  u16* w2_bf   = (u16*)p; p += 1024L*4096*2;
  u16* qin_bf  = (u16*)p; p += 4096L*1024*2;
  u16* kvin_bf = (u16*)p; p += 8192L*1024*2;
  u16* q_bf    = (u16*)p; p += 4L*16*1024*64*2;
  u16* k_bf    = (u16*)p; p += 4L*16*2048*64*2;
  u16* vt_bf   = (u16*)p; p += 4L*16*64*2048*2;
  u16* ctx_bf  = (u16*)p; p += 4096L*1024*2;
  float* il_f  = (float*)p; p += 4L*16*1024*4;
  float* x_f   = (float*)p; p += 4096L*1024*4;
  u16* hln_bf  = (u16*)p; p += 4096L*1024*2;
  u16* gelu_bf = (u16*)p; p += 4096L*4096*2;

  float* x_out    = (float*)d_out;           // [4,1024,1024]
  float* mean_out = x_out + 4194304;         // [4,1024,2048]

  cvt_weights<<<12288, 256, 0, stream>>>(wqkv, wo, w1, w2, wqkv_bf, wo_bf, w1_bf, w2_bf);
  ln_kernel<0><<<4096, 256, 0, stream>>>(tight, nullptr, lnqg, lnqb, qin_bf);
  ln_kernel<1><<<8192, 256, 0, stream>>>(ctxt, nbh, lnkg, lnkb, kvin_bf);
  gemm256_qkv<<<320, 512, 0, stream>>>(qin_bf, kvin_bf, wqkv_bf, bqkv,
                                       q_bf, k_bf, vt_bf);
  flash_fwd<<<512, 256, 0, stream>>>(q_bf, k_bf, vt_bf, ctx_bf, il_f);
  post_attn<<<1024, 256, 0, stream>>>(q_bf, k_bf, il_f, mean_out,
                                      ctx_bf, wo_bf, bo, cg, tight, x_f);
  ln_kernel<0><<<4096, 256, 0, stream>>>(x_f, nullptr, lnfg, lnfb, hln_bf);
  gemm256_ffn1<<<256, 512, 0, stream>>>(hln_bf, w1_bf, 4096, 4096, 1024,
                                        b1, gelu_bf);
  gemm_bt<4,64><<<512, 256, 0, stream>>>(gelu_bf, w2_bf, 4096, 1024, 4096,
                                      b2, fg, x_f, x_out, nullptr, nullptr);
}

// Round 16
// 357.018 us; speedup vs baseline: 1.1734x; 1.1734x over previous
//
#include <hip/hip_runtime.h>
#include <math.h>

typedef unsigned short u16;
typedef __attribute__((ext_vector_type(8))) short bf16x8;
typedef __attribute__((ext_vector_type(4))) float f32x4;

#define MFMA16(a,b,c) __builtin_amdgcn_mfma_f32_16x16x32_bf16(a,b,c,0,0,0)

__device__ __forceinline__ u16 f2bf(float f){
  union { float f; unsigned int u; } x; x.f = f;
  unsigned int r = x.u + 0x7fffu + ((x.u >> 16) & 1u);
  return (u16)(r >> 16);
}

__device__ __forceinline__ void gload16(const void* g, void* lds){
  __builtin_amdgcn_global_load_lds(
    (const __attribute__((address_space(1))) unsigned int*)g,
    (__attribute__((address_space(3))) unsigned int*)lds, 16, 0, 0);
}

// ---------------- weights fp32 -> bf16 ---------------------------------------
__global__ __launch_bounds__(256) void cvt_weights(
    const float* __restrict__ wqkv, const float* __restrict__ wo,
    const float* __restrict__ w1, const float* __restrict__ w2,
    u16* __restrict__ o0, u16* __restrict__ o1,
    u16* __restrict__ o2, u16* __restrict__ o3)
{
  int idx = blockIdx.x * 256 + threadIdx.x;   // quad index, 3145728 total
  const float* src; u16* dst;
  if (idx < 786432)                    { src = wqkv; dst = o0; }
  else if ((idx -= 786432) < 262144)   { src = wo;   dst = o1; }
  else if ((idx -= 262144) < 1048576)  { src = w1;   dst = o2; }
  else { idx -= 1048576;                 src = w2;   dst = o3; }
  float4 v = ((const float4*)src)[idx];
  short4 o;
  o.x = (short)f2bf(v.x); o.y = (short)f2bf(v.y);
  o.z = (short)f2bf(v.z); o.w = (short)f2bf(v.w);
  ((short4*)dst)[idx] = o;
}

// ---------------- LN body (shared) -------------------------------------------
__device__ __forceinline__ void ln_row(
    const float* src, const float* g, const float* be, u16* out, long orow, int t)
{
  float4 v = ((const float4*)src)[t];
  float s  = v.x + v.y + v.z + v.w;
  float ss = v.x*v.x + v.y*v.y + v.z*v.z + v.w*v.w;
  #pragma unroll
  for (int m = 1; m < 64; m <<= 1) { s += __shfl_xor(s, m); ss += __shfl_xor(ss, m); }
  __shared__ float red[8];
  int l = t & 63, w = t >> 6;
  if (l == 0) { red[w*2] = s; red[w*2+1] = ss; }
  __syncthreads();
  s  = red[0] + red[2] + red[4] + red[6];
  ss = red[1] + red[3] + red[5] + red[7];
  float mean = s * (1.0f/1024.0f);
  float var  = ss * (1.0f/1024.0f) - mean*mean;
  float rstd = rsqrtf(var + 1e-5f);
  float4 gv = ((const float4*)g)[t];
  float4 bv = ((const float4*)be)[t];
  short4 o;
  o.x = (short)f2bf((v.x-mean)*rstd*gv.x + bv.x);
  o.y = (short)f2bf((v.y-mean)*rstd*gv.y + bv.y);
  o.z = (short)f2bf((v.z-mean)*rstd*gv.z + bv.z);
  o.w = (short)f2bf((v.w-mean)*rstd*gv.w + bv.w);
  *(short4*)(out + orow*1024 + t*4) = o;
}

// merged input LNs: rows 0..4095 -> LN(tight)->qin ; 4096..12287 -> LN(kv)->kvin
__global__ __launch_bounds__(256) void ln_in(
    const float* __restrict__ tight, const float* __restrict__ ctxt,
    const float* __restrict__ nbh,
    const float* __restrict__ qg, const float* __restrict__ qb,
    const float* __restrict__ kg, const float* __restrict__ kb,
    u16* __restrict__ qout, u16* __restrict__ kvout)
{
  int row = blockIdx.x, t = threadIdx.x;
  if (row < 4096) {
    ln_row(tight + (long)row*1024, qg, qb, qout, row, t);
  } else {
    int r2 = row - 4096;
    int b = r2 >> 11, p = r2 & 2047;
    const float* src = (p < 1024) ? ctxt + ((long)(b*1024 + p))*1024
                                  : nbh + ((long)(b*1024 + p - 1024))*1024;
    ln_row(src, kg, kb, kvout, r2, t);
  }
}

__global__ __launch_bounds__(256) void ln_mid(
    const float* __restrict__ s0,
    const float* __restrict__ g, const float* __restrict__ be,
    u16* __restrict__ out)
{
  int row = blockIdx.x, t = threadIdx.x;
  ln_row(s0 + (long)row*1024, g, be, out, row, t);
}

// ---------------- bf16 GEMM 128-class (qproj / oproj / ffn2) -----------------
template<int EPI, int BM>
__global__ __launch_bounds__(256,2) void gemm_bt(
    const u16* __restrict__ A, const u16* __restrict__ Bt,
    int M, int N, int K,
    const float* __restrict__ bias,
    const float* __restrict__ gamma,
    const float* __restrict__ resid,
    float* __restrict__ outf,
    u16* __restrict__ outb0, u16* __restrict__ outb1)
{
  constexpr int MI = BM / 32;
  __shared__ __align__(16) u16 at[2][BM*64];
  __shared__ __align__(16) u16 bt[2][128*64];
  int nwg = gridDim.x;
  int bidx = (blockIdx.x & 7) * (nwg >> 3) + (blockIdx.x >> 3);
  int nb = N >> 7;
  int tm = bidx / nb, tn = bidx % nb;
  int m0 = tm * BM, n0 = tn << 7;
  int t = threadIdx.x, l = t & 63, w = t >> 6;
  int wr = (w >> 1) * (BM/2), wc = (w & 1) * 64;
  int fr = l & 15, fq = l >> 4;
  f32x4 acc[MI][4] = {};
  int rr = t >> 3;
  int cb = (t & 7) << 4;
  const char* Ab = (const char*)A;
  const char* Bp = (const char*)Bt;
  long ld = (long)K * 2;

#define G_STAGE(s, kt) do {                                                        \
    _Pragma("unroll")                                                              \
    for (int c = 0; c < MI; c++) {                                                 \
      int row = c*32 + rr;                                                         \
      gload16(Ab + (long)(m0 + row)*ld + (long)(kt)*2 + (cb ^ ((row & 7) << 4)),   \
              (char*)at[s] + c*4096 + w*1024);                                     \
    }                                                                              \
    _Pragma("unroll")                                                              \
    for (int c = 0; c < 4; c++) {                                                  \
      int row = c*32 + rr;                                                         \
      gload16(Bp + (long)(n0 + row)*ld + (long)(kt)*2 + (cb ^ ((row & 7) << 4)),   \
              (char*)bt[s] + c*4096 + w*1024);                                     \
    }                                                                              \
  } while (0)

  G_STAGE(0, 0);
  __syncthreads();
  int cur = 0;
  for (int kt = 0; kt < K; kt += 64) {
    if (kt + 64 < K) G_STAGE(cur ^ 1, kt + 64);
    #pragma unroll
    for (int ka = 0; ka < 2; ka++) {
      bf16x8 af[MI], bfv[4];
      #pragma unroll
      for (int i = 0; i < MI; i++) {
        int ra = wr + i*16 + fr;
        af[i] = *(const bf16x8*)((const char*)at[cur] + ra*128 + ((ka*64 + fq*16) ^ ((ra & 7) << 4)));
      }
      #pragma unroll
      for (int j = 0; j < 4; j++) {
        int rb = wc + j*16 + fr;
        bfv[j] = *(const bf16x8*)((const char*)bt[cur] + rb*128 + ((ka*64 + fq*16) ^ ((rb & 7) << 4)));
      }
      #pragma unroll
      for (int i = 0; i < MI; i++)
        #pragma unroll
        for (int j = 0; j < 4; j++)
          acc[i][j] = MFMA16(af[i], bfv[j], acc[i][j]);
    }
    __syncthreads();
    cur ^= 1;
  }
#undef G_STAGE
  #pragma unroll
  for (int i = 0; i < MI; i++) {
    #pragma unroll
    for (int j = 0; j < 4; j++) {
      #pragma unroll
      for (int r = 0; r < 4; r++) {
        int row = m0 + wr + i*16 + fq*4 + r;
        int col = n0 + wc + j*16 + fr;
        float v = acc[i][j][r];
        if constexpr (EPI == 0) {
          float qv = (v + bias[col]) * 0.18033688011112042f;  // (1/8)*log2(e)
          int b = row >> 10, lq = row & 1023, h = col >> 6, hd = col & 63;
          outb0[(((long)(b*16 + h)) << 16) + (lq << 6) + hd] = f2bf(qv);
        } else if constexpr (EPI == 2) {
          float gs = gamma[col]; gs = fminf(fmaxf(gs, -10.f), 10.f);
          long idx = (long)row*1024 + col;
          outf[idx] = resid[idx] + (v + bias[col]) * gs;
        } else if constexpr (EPI == 3) {
          float u = v + bias[col];
          float ge = 0.5f * u * (1.0f + erff(u * 0.70710678118654752f));
          outb0[(long)row*4096 + col] = f2bf(ge);
        } else {
          float gs = gamma[col]; gs = fminf(fmaxf(gs, -10.f), 10.f);
          long idx = (long)row*1024 + col;
          outf[idx] = resid[idx] + (v + bias[col]) * gs;
        }
      }
    }
  }
}

// ---------------- 256^2-tile 8-phase GEMM (kvproj EPI=1, ffn1 EPI=3) ---------
// Grid MUST be <=256 blocks (1 block/CU at 128KB LDS; >256 => 2 scheduling
// rounds, ~2x time -- r15 lesson).
template<int EPI>
__global__ __launch_bounds__(512, 2) void gemm256(
    const u16* __restrict__ A, const u16* __restrict__ Bt,
    int M, int N, int K,
    const float* __restrict__ bias,
    u16* __restrict__ outb0, u16* __restrict__ outb1)
{
  __shared__ __align__(16) u16 As[2][256*64];
  __shared__ __align__(16) u16 Bs[2][256*64];
  int nwg = gridDim.x;
  int bidx = (blockIdx.x & 7) * (nwg >> 3) + (blockIdx.x >> 3);  // T1 XCD chunk
  int nb = N >> 8;
  int tm = bidx / nb, tn = bidx % nb;
  int m0 = tm << 8, n0 = tn << 8;
  int t = threadIdx.x, l = t & 63, w = t >> 6;
  int wm = w >> 2, wn = w & 3;
  int fr = l & 15, fq = l >> 4;
  int sr = t >> 3;
  int scb = (t & 7) << 4;
  int s7 = (sr & 7) << 4;
  const char* Ab = (const char*)A;
  const char* Bp = (const char*)Bt;
  long ld = (long)K * 2;

#define STAGE_AQ(slot, kt, q) do {                                               \
    int grow = (sr < 32) ? ((q)*32 + sr) : (128 + (q)*32 + sr - 32);             \
    int abase = (w < 4) ? ((q)*32 + w*8) : (128 + (q)*32 + (w - 4)*8);           \
    gload16(Ab + (long)(m0 + grow)*ld + (long)(kt)*2 + (scb ^ s7),               \
            (char*)As[slot] + abase*128);                                        \
  } while (0)
#define STAGE_BH(slot, kt, h) do {                                               \
    int r0 = (h)*128 + sr;                                                       \
    gload16(Bp + (long)(n0 + r0)*ld + (long)(kt)*2 + (scb ^ s7),                 \
            (char*)Bs[slot] + ((h)*128 + w*8)*128);                              \
    gload16(Bp + (long)(n0 + r0 + 64)*ld + (long)(kt)*2 + (scb ^ s7),            \
            (char*)Bs[slot] + ((h)*128 + 64 + w*8)*128);                         \
  } while (0)

  f32x4 acc[8][4] = {};
  int NT = K >> 6;

  STAGE_BH(0, 0, 0); STAGE_BH(0, 0, 1);
  STAGE_AQ(0, 0, 0); STAGE_AQ(0, 0, 1); STAGE_AQ(0, 0, 2); STAGE_AQ(0, 0, 3);
  STAGE_BH(1, 64, 0); STAGE_BH(1, 64, 1);
  asm volatile("s_waitcnt vmcnt(4)" ::: "memory");
  __builtin_amdgcn_s_barrier();
  asm volatile("" ::: "memory");

#define MFMA_PHASE(mibase)                                                       \
    __builtin_amdgcn_s_setprio(1);                                               \
    _Pragma("unroll")                                                            \
    for (int nj = 0; nj < 4; nj++) {                                             \
      acc[(mibase)][nj]   = MFMA16(a00, bfr[nj][0], acc[(mibase)][nj]);          \
      acc[(mibase)][nj]   = MFMA16(a01, bfr[nj][1], acc[(mibase)][nj]);          \
      acc[(mibase)+1][nj] = MFMA16(a10, bfr[nj][0], acc[(mibase)+1][nj]);        \
      acc[(mibase)+1][nj] = MFMA16(a11, bfr[nj][1], acc[(mibase)+1][nj]);        \
    }                                                                            \
    __builtin_amdgcn_s_setprio(0);

#define READ_A(p)                                                                \
    int r0_ = wm*128 + (2*(p))*16 + fr;                                          \
    int r1_ = r0_ + 16;                                                          \
    bf16x8 a00 = *(const bf16x8*)(Ab_s + r0_*128 + ((fq*16) ^ ((r0_ & 7) << 4)));        \
    bf16x8 a01 = *(const bf16x8*)(Ab_s + r0_*128 + ((64 + fq*16) ^ ((r0_ & 7) << 4)));   \
    bf16x8 a10 = *(const bf16x8*)(Ab_s + r1_*128 + ((fq*16) ^ ((r1_ & 7) << 4)));        \
    bf16x8 a11 = *(const bf16x8*)(Ab_s + r1_*128 + ((64 + fq*16) ^ ((r1_ & 7) << 4)));

  for (int tt = 0; tt < NT; tt++) {
    int s = tt & 1;
    const char* Ab_s = (const char*)As[s];
    const char* Bb_s = (const char*)Bs[s];
    int kt1 = (tt + 1) << 6, kt2 = (tt + 2) << 6;
    bf16x8 bfr[4][2];
    {
      #pragma unroll
      for (int nj = 0; nj < 4; nj++) {
        int rb = wn*64 + nj*16 + fr;
        bfr[nj][0] = *(const bf16x8*)(Bb_s + rb*128 + ((fq*16) ^ ((rb & 7) << 4)));
        bfr[nj][1] = *(const bf16x8*)(Bb_s + rb*128 + ((64 + fq*16) ^ ((rb & 7) << 4)));
      }
      READ_A(0)
      if (tt + 1 < NT) { STAGE_AQ(s ^ 1, kt1, 0); STAGE_AQ(s ^ 1, kt1, 1); }
      asm volatile("s_waitcnt lgkmcnt(8)" ::: "memory");
      __builtin_amdgcn_s_barrier();
      asm volatile("s_waitcnt lgkmcnt(0)" ::: "memory");
      MFMA_PHASE(0)
      __builtin_amdgcn_s_barrier();
    }
    {
      READ_A(1)
      if (tt + 1 < NT) { STAGE_AQ(s ^ 1, kt1, 2); STAGE_AQ(s ^ 1, kt1, 3); }
      __builtin_amdgcn_s_barrier();
      asm volatile("s_waitcnt lgkmcnt(0)" ::: "memory");
      MFMA_PHASE(2)
      __builtin_amdgcn_s_barrier();
    }
    {
      READ_A(2)
      if (tt + 2 < NT) STAGE_BH(s, kt2, 0);
      __builtin_amdgcn_s_barrier();
      asm volatile("s_waitcnt lgkmcnt(0)" ::: "memory");
      MFMA_PHASE(4)
      __builtin_amdgcn_s_barrier();
    }
    {
      READ_A(3)
      if (tt + 2 < NT) STAGE_BH(s, kt2, 1);
      __builtin_amdgcn_s_barrier();
      asm volatile("s_waitcnt lgkmcnt(0)" ::: "memory");
      MFMA_PHASE(6)
      if (tt + 1 < NT) {
        if (tt + 2 < NT) { asm volatile("s_waitcnt vmcnt(4)" ::: "memory"); }
        else             { asm volatile("s_waitcnt vmcnt(0)" ::: "memory"); }
      }
      __builtin_amdgcn_s_barrier();
      asm volatile("" ::: "memory");
    }
  }
#undef READ_A
#undef MFMA_PHASE
#undef STAGE_AQ
#undef STAGE_BH

  #pragma unroll
  for (int mi = 0; mi < 8; mi++) {
    #pragma unroll
    for (int nj = 0; nj < 4; nj++) {
      #pragma unroll
      for (int r = 0; r < 4; r++) {
        int row = m0 + wm*128 + mi*16 + fq*4 + r;
        int col = n0 + wn*64 + nj*16 + fr;
        float v = acc[mi][nj][r];
        if constexpr (EPI == 1) {
          float u = v + bias[col];
          int b = row >> 11, p = row & 2047;
          if (col < 1024) {
            int h = col >> 6, hd = col & 63;
            outb0[(((long)((b*16 + h)*2048 + p)) << 6) + hd] = f2bf(u);
          } else {
            int c2 = col - 1024, h = c2 >> 6, hd = c2 & 63;
            outb1[(((long)((b*16 + h)*64 + hd)) << 11) + p] = f2bf(u);  // V^T
          }
        } else {  // EPI == 3: ffn1 gelu
          float u = v + bias[col];
          float ge = 0.5f * u * (1.0f + erff(u * 0.70710678118654752f));
          outb0[(long)row*4096 + col] = f2bf(ge);
        }
      }
    }
  }
}

// ---------------- flash attention fwd (r13 version, 73us) --------------------
__global__ __launch_bounds__(256, 3) void flash_fwd(
    const u16* __restrict__ q, const u16* __restrict__ k,
    const u16* __restrict__ vt, u16* __restrict__ ctx,
    float* __restrict__ ilout)
{
  __shared__ __align__(16) u16 ks[2][64*64];
  __shared__ __align__(16) u16 vs[2][64*64];
  __shared__ __align__(16) char ps[4*4096];
  int nwg = gridDim.x;
  int bid = (blockIdx.x & 7) * (nwg >> 3) + (blockIdx.x >> 3);
  int qt = bid & 7, h = (bid >> 3) & 15, b = bid >> 7;
  int q0 = qt << 7;
  int t = threadIdx.x, l = t & 63, w = t >> 6;
  int fr = l & 15, fq = l >> 4;
  const char* qb = (const char*)(q  + (((long)(b*16 + h)) << 16));
  const char* kb = (const char*)(k  + (((long)(b*16 + h)) << 17));
  const char* vb = (const char*)(vt + (((long)(b*16 + h)) << 17));
  char* psw = ps + w*4096;
  int rr = t >> 3;
  int sc = (t & 7) << 4;

  #pragma unroll
  for (int c = 0; c < 2; c++) {
    int row = c*32 + rr;
    gload16(kb + (long)row*128 + (sc ^ ((row & 7) << 4)), (char*)ks[0] + c*4096 + w*1024);
    gload16(vb + (long)row*4096 + (sc ^ ((row & 7) << 4)), (char*)vs[0] + c*4096 + w*1024);
  }
  {
    int qr = l >> 3;
    #pragma unroll
    for (int c = 0; c < 4; c++) {
      int row = c*8 + qr;
      gload16(qb + (long)(q0 + w*32 + row)*128 + (sc ^ ((row & 7) << 4)), psw + c*1024);
    }
  }
  asm volatile("s_waitcnt vmcnt(0)" ::: "memory");
  bf16x8 qf[2][2];
  #pragma unroll
  for (int rf = 0; rf < 2; rf++) {
    int row = rf*16 + fr;
    qf[rf][0] = *(const bf16x8*)(psw + row*128 + ((fq*16) ^ ((row & 7) << 4)));
    qf[rf][1] = *(const bf16x8*)(psw + row*128 + ((64 + fq*16) ^ ((row & 7) << 4)));
  }
  asm volatile("s_waitcnt lgkmcnt(0)" ::: "memory");
  __builtin_amdgcn_s_barrier();
  asm volatile("" ::: "memory");

  f32x4 cacc[2][4] = {};
  f32x4 lrun[2] = {{0.f,0.f,0.f,0.f},{0.f,0.f,0.f,0.f}};
  int cur = 0;
  for (int kt = 0; kt < 2048; kt += 64) {
    int notlast = (kt + 64 < 2048);
    if (notlast) {
      #pragma unroll
      for (int c = 0; c < 2; c++) {
        int row = c*32 + rr;
        gload16(vb + (long)row*4096 + (long)(kt + 64)*2 + (sc ^ ((row & 7) << 4)),
                (char*)vs[cur ^ 1] + c*4096 + w*1024);
        gload16(kb + (long)(kt + 64 + row)*128 + (sc ^ ((row & 7) << 4)),
                (char*)ks[cur ^ 1] + c*4096 + w*1024);
      }
    }
    __builtin_amdgcn_sched_barrier(0);
    const char* ksb = (const char*)ks[cur];
    f32x4 sf[2][4];
    __builtin_amdgcn_s_setprio(1);
    #pragma unroll
    for (int cf = 0; cf < 4; cf++) {
      int row = cf*16 + fr;
      bf16x8 kf0 = *(const bf16x8*)(ksb + row*128 + ((fq*16) ^ ((row & 7) << 4)));
      bf16x8 kf1 = *(const bf16x8*)(ksb + row*128 + ((64 + fq*16) ^ ((row & 7) << 4)));
      #pragma unroll
      for (int rf = 0; rf < 2; rf++) {
        f32x4 a = {};
        a = MFMA16(qf[rf][0], kf0, a);
        sf[rf][cf] = MFMA16(qf[rf][1], kf1, a);
      }
    }
    __builtin_amdgcn_s_setprio(0);
    #pragma unroll
    for (int rf = 0; rf < 2; rf++)
      #pragma unroll
      for (int cf = 0; cf < 4; cf++)
        #pragma unroll
        for (int r = 0; r < 4; r++) {
          float pv = exp2f(sf[rf][cf][r]);
          lrun[rf][r] += pv;
          union { float f; unsigned int u; } pu; pu.f = pv;
          int prow = rf*16 + fq*4 + r;
          *(u16*)(psw + prow*128 + (((cf*16 + fr) << 1) ^ ((prow & 7) << 4))) = (u16)(pu.u >> 16);
        }
    bf16x8 pa[2][2];
    #pragma unroll
    for (int rf = 0; rf < 2; rf++) {
      int row = rf*16 + fr;
      pa[rf][0] = *(const bf16x8*)(psw + row*128 + ((fq*16) ^ ((row & 7) << 4)));
      pa[rf][1] = *(const bf16x8*)(psw + row*128 + ((64 + fq*16) ^ ((row & 7) << 4)));
    }
    __builtin_amdgcn_s_setprio(1);
    #pragma unroll
    for (int cfd = 0; cfd < 4; cfd++) {
      int hd = cfd*16 + fr;
      bf16x8 vf0 = *(const bf16x8*)((const char*)vs[cur] + hd*128 + ((fq*16) ^ ((hd & 7) << 4)));
      bf16x8 vf1 = *(const bf16x8*)((const char*)vs[cur] + hd*128 + ((64 + fq*16) ^ ((hd & 7) << 4)));
      #pragma unroll
      for (int rf = 0; rf < 2; rf++) {
        cacc[rf][cfd] = MFMA16(pa[rf][0], vf0, cacc[rf][cfd]);
        cacc[rf][cfd] = MFMA16(pa[rf][1], vf1, cacc[rf][cfd]);
      }
    }
    __builtin_amdgcn_s_setprio(0);
    if (notlast) {
      asm volatile("s_waitcnt vmcnt(0)" ::: "memory");
      __builtin_amdgcn_s_barrier();
      asm volatile("" ::: "memory");
    }
    cur ^= 1;
  }
  #pragma unroll
  for (int rf = 0; rf < 2; rf++) {
    float il4[4];
    #pragma unroll
    for (int r = 0; r < 4; r++) {
      float s = lrun[rf][r];
      #pragma unroll
      for (int msk = 1; msk < 16; msk <<= 1) s += __shfl_xor(s, msk, 16);
      il4[r] = 1.0f / s;
    }
    #pragma unroll
    for (int cf = 0; cf < 4; cf++)
      #pragma unroll
      for (int r = 0; r < 4; r++) {
        int row = q0 + w*32 + rf*16 + fq*4 + r;
        int col = h*64 + cf*16 + fr;
        ctx[(long)(b*1024 + row)*1024 + col] = f2bf(cacc[rf][cf][r] * il4[r]);
      }
    if (fr == 0) {
      #pragma unroll
      for (int r = 0; r < 4; r++) {
        int row = q0 + w*32 + rf*16 + fq*4 + r;
        long idx = (((long)(b*16 + h)) << 10) + row;
        ilout[idx] = il4[r];
      }
    }
  }
}

// ---------------- attn mean over heads (GEMM-style, double-buffered) ---------
__global__ __launch_bounds__(256,2) void attn_mean(
    const u16* __restrict__ q, const u16* __restrict__ k,
    const float* __restrict__ il,
    float* __restrict__ out)
{
  __shared__ __align__(16) u16 qs[2][128*64];
  __shared__ __align__(16) u16 ks[2][128*64];
  __shared__ __align__(16) float ml[2][128];
  int nwg = gridDim.x;
  int bid = (blockIdx.x & 7) * (nwg >> 3) + (blockIdx.x >> 3);
  int kt = bid & 15, qt = (bid >> 4) & 7, b = bid >> 7;
  int q0 = qt << 7, k0 = kt << 7;
  int t = threadIdx.x, l = t & 63, w = t >> 6;
  int wr = (w >> 1) << 6, wc = (w & 1) << 6;
  int fr = l & 15, fq = l >> 4;
  int rr = t >> 3, cbb = (t & 7) << 4;
  const long bh = (long)b * 16;

#define AM_STAGE(hh, s) do {                                                        \
    const char* qb_ = (const char*)(q + ((bh + (hh)) << 16)) + (long)q0*128;        \
    const char* kb_ = (const char*)(k + ((bh + (hh)) << 17)) + (long)k0*128;        \
    _Pragma("unroll")                                                               \
    for (int c = 0; c < 4; c++) {                                                   \
      int row = c*32 + rr;                                                          \
      int sw = cbb ^ ((row & 7) << 4);                                              \
      gload16(qb_ + (long)row*128 + sw, (char*)qs[s] + c*4096 + w*1024);            \
      gload16(kb_ + (long)row*128 + sw, (char*)ks[s] + c*4096 + w*1024);            \
    }                                                                               \
    if (w == 0 && l < 32) {                                                         \
      gload16((const char*)(il + ((bh + (hh)) << 10) + q0) + l*16, (char*)ml[s]);   \
    }                                                                               \
  } while (0)

  AM_STAGE(0, 0);
  asm volatile("s_waitcnt vmcnt(0)" ::: "memory");
  __builtin_amdgcn_s_barrier();
  asm volatile("" ::: "memory");

  f32x4 macc[4][4] = {};
  for (int h = 0; h < 16; h++) {
    int cur = h & 1;
    if (h < 15) AM_STAGE(h + 1, cur ^ 1);
    const char* qsb = (const char*)qs[cur];
    const char* ksb = (const char*)ks[cur];
    const float* mlb = ml[cur];
    f32x4 ir4[4];
    #pragma unroll
    for (int i = 0; i < 4; i++)
      ir4[i] = *(const f32x4*)(mlb + wr + i*16 + fq*4);
    bf16x8 af[4][2], bf[4][2];
    #pragma unroll
    for (int i = 0; i < 4; i++) {
      int ra = wr + i*16 + fr;
      int rb = wc + i*16 + fr;
      af[i][0] = *(const bf16x8*)(qsb + ra*128 + ((fq*16) ^ ((ra & 7) << 4)));
      af[i][1] = *(const bf16x8*)(qsb + ra*128 + ((64 + fq*16) ^ ((ra & 7) << 4)));
      bf[i][0] = *(const bf16x8*)(ksb + rb*128 + ((fq*16) ^ ((rb & 7) << 4)));
      bf[i][1] = *(const bf16x8*)(ksb + rb*128 + ((64 + fq*16) ^ ((rb & 7) << 4)));
    }
    #pragma unroll
    for (int j = 0; j < 4; j++) {
      f32x4 sf[4];
      __builtin_amdgcn_s_setprio(1);
      #pragma unroll
      for (int i = 0; i < 4; i++) {
        f32x4 a = MFMA16(af[i][0], bf[j][0], {});
        sf[i] = MFMA16(af[i][1], bf[j][1], a);
      }
      __builtin_amdgcn_s_setprio(0);
      #pragma unroll
      for (int i = 0; i < 4; i++)
        #pragma unroll
        for (int r = 0; r < 4; r++)
          macc[i][j][r] += exp2f(sf[i][r]) * ir4[i][r];
    }
    asm volatile("s_waitcnt vmcnt(0)" ::: "memory");
    __builtin_amdgcn_s_barrier();
    asm volatile("" ::: "memory");
  }
#undef AM_STAGE
  #pragma unroll
  for (int i = 0; i < 4; i++)
    #pragma unroll
    for (int j = 0; j < 4; j++)
      #pragma unroll
      for (int r = 0; r < 4; r++) {
        int row = q0 + wr + i*16 + fq*4 + r;
        int col = k0 + wc + j*16 + fr;
        out[((long)(b*1024 + row) << 11) + col] = macc[i][j][r] * 0.0625f;
      }
}

extern "C" void kernel_launch(void* const* d_in, const int* in_sizes, int n_in,
                              void* d_out, int out_size, void* d_ws, size_t ws_size,
                              hipStream_t stream)
{
  (void)in_sizes; (void)n_in; (void)out_size; (void)ws_size;
  const float* tight = (const float*)d_in[0];
  const float* ctxt  = (const float*)d_in[1];
  const float* nbh   = (const float*)d_in[2];
  const float* lnqg  = (const float*)d_in[3];
  const float* lnqb  = (const float*)d_in[4];
  const float* lnkg  = (const float*)d_in[5];
  const float* lnkb  = (const float*)d_in[6];
  const float* wqkv  = (const float*)d_in[7];
  const float* bqkv  = (const float*)d_in[8];
  const float* wo    = (const float*)d_in[9];
  const float* bo    = (const float*)d_in[10];
  const float* cg    = (const float*)d_in[11];
  const float* lnfg  = (const float*)d_in[12];
  const float* lnfb  = (const float*)d_in[13];
  const float* w1    = (const float*)d_in[14];
  const float* b1    = (const float*)d_in[15];
  const float* w2    = (const float*)d_in[16];
  const float* b2    = (const float*)d_in[17];
  const float* fg    = (const float*)d_in[18];

  char* p = (char*)d_ws;
  u16* wqkv_bf = (u16*)p; p += 3072L*1024*2;
  u16* wo_bf   = (u16*)p; p += 1024L*1024*2;
  u16* w1_bf   = (u16*)p; p += 4096L*1024*2;
  u16* w2_bf   = (u16*)p; p += 1024L*4096*2;
  u16* qin_bf  = (u16*)p; p += 4096L*1024*2;
  u16* kvin_bf = (u16*)p; p += 8192L*1024*2;
  u16* q_bf    = (u16*)p; p += 4L*16*1024*64*2;
  u16* k_bf    = (u16*)p; p += 4L*16*2048*64*2;
  u16* vt_bf   = (u16*)p; p += 4L*16*64*2048*2;
  u16* ctx_bf  = (u16*)p; p += 4096L*1024*2;
  float* il_f  = (float*)p; p += 4L*16*1024*4;
  float* x_f   = (float*)p; p += 4096L*1024*4;
  u16* hln_bf  = (u16*)p; p += 4096L*1024*2;
  u16* gelu_bf = (u16*)p; p += 4096L*4096*2;

  float* x_out    = (float*)d_out;           // [4,1024,1024]
  float* mean_out = x_out + 4194304;         // [4,1024,2048]

  cvt_weights<<<12288, 256, 0, stream>>>(wqkv, wo, w1, w2, wqkv_bf, wo_bf, w1_bf, w2_bf);
  ln_in<<<12288, 256, 0, stream>>>(tight, ctxt, nbh, lnqg, lnqb, lnkg, lnkb,
                                   qin_bf, kvin_bf);
  gemm_bt<0,64><<<512, 256, 0, stream>>>(qin_bf, wqkv_bf, 4096, 1024, 1024,
                                      bqkv, nullptr, nullptr, nullptr, q_bf, nullptr);
  gemm256<1><<<256, 512, 0, stream>>>(kvin_bf, wqkv_bf + 1024L*1024, 8192, 2048, 1024,
                                      bqkv + 1024, k_bf, vt_bf);
  flash_fwd<<<512, 256, 0, stream>>>(q_bf, k_bf, vt_bf, ctx_bf, il_f);
  attn_mean<<<512, 256, 0, stream>>>(q_bf, k_bf, il_f, mean_out);
  gemm_bt<2,64><<<512, 256, 0, stream>>>(ctx_bf, wo_bf, 4096, 1024, 1024,
                                      bo, cg, tight, x_f, nullptr, nullptr);
  ln_mid<<<4096, 256, 0, stream>>>(x_f, lnfg, lnfb, hln_bf);
  gemm256<3><<<256, 512, 0, stream>>>(hln_bf, w1_bf, 4096, 4096, 1024,
                                      b1, gelu_bf, nullptr);
  gemm_bt<4,64><<<512, 256, 0, stream>>>(gelu_bf, w2_bf, 4096, 1024, 4096,
                                      b2, fg, x_f, x_out, nullptr, nullptr);
}